// Round 2
// baseline (3306.420 us; speedup 1.0000x reference)
//
#include <hip/hip_runtime.h>
#include <hip/hip_bf16.h>

#define S_LEN 2048
#define DMODEL 1024
#define NH 16
#define DK 64
#define BATCH 4

using bf16 = __hip_bfloat16;
using bf162 = __hip_bfloat162;

__device__ inline float loadF(const float* p, size_t i) { return p[i]; }
__device__ inline float loadF(const bf16* p, size_t i) { return __bfloat162float(p[i]); }

__device__ inline void storeF(float* p, size_t i, float v) { p[i] = v; }
__device__ inline void storeF(bf16* p, size_t i, float v) { p[i] = __float2bfloat16(v); }

// ---------------- GEMM: C = A @ W + bias ----------------
// A: [M, 1024] row-major (AT = float or bf16); W: [1024, 1024] float row-major (W[k][n])
// MODE 0: C row-major [M, 1024]
// MODE 1: C as [B, H, S, DK] with m = b*S+s, n = h*DK+dk  (QKV head split)
template <int MODE, typename AT, typename OT>
__global__ __launch_bounds__(256) void gemm_bias_kernel(
    const AT* __restrict__ A, const float* __restrict__ W,
    const float* __restrict__ bias, OT* __restrict__ C, int M)
{
    const int BM = 64, BN = 64, BK = 32;
    __shared__ float As[BK][BM + 4];
    __shared__ float Bs[BK][BN + 4];
    int t = threadIdx.x;
    int m0 = blockIdx.x * BM;
    int n0 = blockIdx.y * BN;
    int tx = t % 16, ty = t / 16;
    float acc[4][4] = {};

    for (int k0 = 0; k0 < 1024; k0 += BK) {
        // A tile: 64(m) x 32(k), coalesced over k
        {
            int k = t % 32;
            int mb = t / 32;  // 0..7
            #pragma unroll
            for (int i = 0; i < 8; i++) {
                int m = mb * 8 + i;
                As[k][m] = loadF(A, (size_t)(m0 + m) * 1024 + k0 + k);
            }
        }
        // B tile: 32(k) x 64(n), coalesced over n
        {
            int n = t % 64;
            int kb = t / 64;  // 0..3
            #pragma unroll
            for (int i = 0; i < 8; i++) {
                int k = kb * 8 + i;
                Bs[k][n] = W[(size_t)(k0 + k) * 1024 + n0 + n];
            }
        }
        __syncthreads();
        #pragma unroll
        for (int kk = 0; kk < BK; kk++) {
            float a[4], b[4];
            #pragma unroll
            for (int i = 0; i < 4; i++) a[i] = As[kk][ty * 4 + i];
            #pragma unroll
            for (int j = 0; j < 4; j++) b[j] = Bs[kk][tx * 4 + j];
            #pragma unroll
            for (int i = 0; i < 4; i++)
                #pragma unroll
                for (int j = 0; j < 4; j++)
                    acc[i][j] = fmaf(a[i], b[j], acc[i][j]);
        }
        __syncthreads();
    }

    #pragma unroll
    for (int i = 0; i < 4; i++) {
        int m = m0 + ty * 4 + i;
        #pragma unroll
        for (int j = 0; j < 4; j++) {
            int n = n0 + tx * 4 + j;
            float v = acc[i][j] + bias[n];
            size_t idx;
            if (MODE == 0) {
                idx = (size_t)m * 1024 + n;
            } else {
                int b = m / S_LEN, s = m % S_LEN;
                int h = n / DK, dk = n % DK;
                idx = (((size_t)(b * NH + h)) * S_LEN + s) * DK + dk;
            }
            storeF(C, idx, v);
        }
    }
}

// ---------------- Flash attention (causal) ----------------
// Q,K,V: [B,H,S,DK] bf16. Output attn_out: [B,S,H,DK] bf16.
// One thread = one query row; block = 256 consecutive queries of one (b,h).
#define KT 128  // key tile
#define CH 8    // softmax chunk

__global__ __launch_bounds__(256) void attn_kernel(
    const bf16* __restrict__ Qg, const bf16* __restrict__ Kg,
    const bf16* __restrict__ Vg, bf16* __restrict__ Og)
{
    __shared__ bf162 Ks[KT * DK / 2];  // [128][32] bf162
    __shared__ bf162 Vs[KT * DK / 2];

    int bh = blockIdx.x;            // b*NH + h
    int q0 = blockIdx.y * 256;
    int t = threadIdx.x;
    int q = q0 + t;
    int b = bh / NH;
    int h = bh % NH;

    // load this thread's query row into registers (fp32)
    float qv[DK];
    {
        const uint4* qp = (const uint4*)(Qg + ((size_t)bh * S_LEN + q) * DK);
        #pragma unroll
        for (int i = 0; i < 8; i++) {
            uint4 u = qp[i];
            const bf162* p2 = (const bf162*)&u;
            #pragma unroll
            for (int j = 0; j < 4; j++) {
                float2 f = __bfloat1622float2(p2[j]);
                qv[i * 8 + j * 2] = f.x;
                qv[i * 8 + j * 2 + 1] = f.y;
            }
        }
    }

    float o[DK] = {};
    float mmax = -1e30f, l = 0.f;
    const size_t baseKV = (size_t)bh * S_LEN * DK;
    int ntiles = q0 / KT + 2;  // keys 0 .. q0+255 inclusive

    for (int tile = 0; tile < ntiles; tile++) {
        int k0 = tile * KT;
        // cooperative load of K,V tile: 128x64 bf16 = 1024 uint4 each
        {
            const uint4* kp = (const uint4*)(Kg + baseKV + (size_t)k0 * DK);
            const uint4* vp = (const uint4*)(Vg + baseKV + (size_t)k0 * DK);
            uint4* ks = (uint4*)Ks;
            uint4* vs = (uint4*)Vs;
            #pragma unroll
            for (int i = 0; i < 4; i++) {
                ks[t + 256 * i] = kp[t + 256 * i];
                vs[t + 256 * i] = vp[t + 256 * i];
            }
        }
        __syncthreads();

        int nvalid = q - k0 + 1;  // causal: keys k0..k0+nvalid-1 allowed
        if (nvalid > KT) nvalid = KT;

        for (int c0 = 0; c0 < KT; c0 += CH) {
            if (c0 >= nvalid) break;  // chunk loop only; no barrier inside
            float sc[CH];
            float cmax = -1e30f;
            #pragma unroll
            for (int j = 0; j < CH; j++) {
                int kk = c0 + j;
                float s = 0.f;
                const bf162* kr = Ks + kk * 32;
                #pragma unroll
                for (int dd = 0; dd < 32; dd++) {
                    float2 kf = __bfloat1622float2(kr[dd]);
                    s = fmaf(qv[2 * dd], kf.x, s);
                    s = fmaf(qv[2 * dd + 1], kf.y, s);
                }
                s *= 0.125f;  // 1/sqrt(64)
                if (kk >= nvalid) s = -1e30f;
                sc[j] = s;
                cmax = fmaxf(cmax, s);
            }
            float mnew = fmaxf(mmax, cmax);
            float alpha = __expf(mmax - mnew);
            #pragma unroll
            for (int d = 0; d < DK; d++) o[d] *= alpha;
            l *= alpha;
            mmax = mnew;
            #pragma unroll
            for (int j = 0; j < CH; j++) {
                float p = __expf(sc[j] - mnew);
                l += p;
                const bf162* vr = Vs + (c0 + j) * 32;
                #pragma unroll
                for (int dd = 0; dd < 32; dd++) {
                    float2 vf = __bfloat1622float2(vr[dd]);
                    o[2 * dd] = fmaf(p, vf.x, o[2 * dd]);
                    o[2 * dd + 1] = fmaf(p, vf.y, o[2 * dd + 1]);
                }
            }
        }
        __syncthreads();
    }

    // write attn_out [B, S, H, DK]
    float inv = 1.f / l;
    size_t outBase = (((size_t)b * S_LEN + q) * NH + h) * DK;
    bf162* op = (bf162*)(Og + outBase);
    #pragma unroll
    for (int dd = 0; dd < 32; dd++) {
        bf162 r;
        r.x = __float2bfloat16(o[2 * dd] * inv);
        r.y = __float2bfloat16(o[2 * dd + 1] * inv);
        op[dd] = r;
    }
}

extern "C" void kernel_launch(void* const* d_in, const int* in_sizes, int n_in,
                              void* d_out, int out_size, void* d_ws, size_t ws_size,
                              hipStream_t stream) {
    const float* x  = (const float*)d_in[0];
    // d_in[1] = attn_mask (int32 tril) — causality implemented directly
    const float* Wq = (const float*)d_in[2];
    const float* bq = (const float*)d_in[3];
    const float* Wk = (const float*)d_in[4];
    const float* bk = (const float*)d_in[5];
    const float* Wv = (const float*)d_in[6];
    const float* bv = (const float*)d_in[7];
    const float* Wo = (const float*)d_in[8];
    const float* bo = (const float*)d_in[9];
    float* out = (float*)d_out;

    char* ws = (char*)d_ws;
    const size_t TEN = (size_t)BATCH * S_LEN * DMODEL * sizeof(bf16);  // 16 MiB
    bf16* Q  = (bf16*)(ws);
    bf16* Kt = (bf16*)(ws + TEN);
    bf16* Vt = (bf16*)(ws + 2 * TEN);
    bf16* AO = (bf16*)(ws + 3 * TEN);

    const int M = BATCH * S_LEN;  // 8192
    dim3 gg(M / 64, DMODEL / 64);
    dim3 gb(256);

    hipLaunchKernelGGL((gemm_bias_kernel<1, float, bf16>), gg, gb, 0, stream, x, Wq, bq, Q, M);
    hipLaunchKernelGGL((gemm_bias_kernel<1, float, bf16>), gg, gb, 0, stream, x, Wk, bk, Kt, M);
    hipLaunchKernelGGL((gemm_bias_kernel<1, float, bf16>), gg, gb, 0, stream, x, Wv, bv, Vt, M);

    dim3 ga(BATCH * NH, S_LEN / 256);
    hipLaunchKernelGGL(attn_kernel, ga, gb, 0, stream, Q, Kt, Vt, AO);

    hipLaunchKernelGGL((gemm_bias_kernel<0, bf16, float>), gg, gb, 0, stream, AO, Wo, bo, out, M);
}

// Round 3
// 1808.089 us; speedup vs baseline: 1.8287x; 1.8287x over previous
//
#include <hip/hip_runtime.h>
#include <hip/hip_bf16.h>
#include <stdint.h>

#define S_LEN 2048
#define DMODEL 1024
#define NH 16
#define DK 64
#define BATCH 4
#define KDIM 1024

using bf16 = __hip_bfloat16;
using bf162 = __hip_bfloat162;

typedef __bf16 v_bf16x8 __attribute__((ext_vector_type(8)));
typedef float v_f32x4 __attribute__((ext_vector_type(4)));

// ---------- prep: fp32 -> bf16 elementwise (4 elems/thread) ----------
struct alignas(8) BF4 { bf16 a, b, c, d; };

__global__ __launch_bounds__(256) void cvt_f32_bf16(const float* __restrict__ in,
                                                    bf16* __restrict__ out) {
    size_t i = ((size_t)blockIdx.x * 256 + threadIdx.x) * 4;
    float4 v = *(const float4*)(in + i);
    BF4 r;
    r.a = __float2bfloat16(v.x);
    r.b = __float2bfloat16(v.y);
    r.c = __float2bfloat16(v.z);
    r.d = __float2bfloat16(v.w);
    *(BF4*)(out + i) = r;
}

// ---------- prep: W[k][n] fp32 -> Wt[n][k] bf16 (tiled transpose) ----------
__global__ __launch_bounds__(256) void transpose_cvt(const float* __restrict__ W,
                                                     bf16* __restrict__ Wt) {
    __shared__ float tile[32][33];
    int tx = threadIdx.x, ty = threadIdx.y;
    int k0 = blockIdx.x * 32, n0 = blockIdx.y * 32;
    #pragma unroll
    for (int i = 0; i < 4; i++) {
        int k = k0 + ty + 8 * i;
        tile[ty + 8 * i][tx] = W[(size_t)k * DMODEL + n0 + tx];
    }
    __syncthreads();
    #pragma unroll
    for (int i = 0; i < 4; i++) {
        int n = n0 + ty + 8 * i;
        Wt[(size_t)n * DMODEL + k0 + tx] = __float2bfloat16(tile[tx][ty + 8 * i]);
    }
}

// ---------- MFMA GEMM: C = A @ W + bias ----------
// A: [M,1024] bf16 row-major. Bt: [1024,1024] bf16 with Bt[n][k] = W[k][n].
// MODE 0: C fp32 row-major [M,1024].  MODE 1: C bf16 as [B,H,S,DK].
// 128x128 tile, BK=32, 4 waves, each wave 64x64 via 4x4 mfma_16x16x32 tiles.
template <int MODE>
__global__ __launch_bounds__(256) void gemm_mfma(
    const bf16* __restrict__ A, const bf16* __restrict__ Bt,
    const float* __restrict__ bias, void* __restrict__ Cv)
{
    __shared__ __align__(16) short As[128 * 32];
    __shared__ __align__(16) short Bs[128 * 32];
    const int t = threadIdx.x;
    const int lane = t & 63;
    const int wave = t >> 6;
    const int m0 = blockIdx.x * 128;
    const int n0 = blockIdx.y * 128;
    const int wRow = (wave >> 1) * 64;
    const int wCol = (wave & 1) * 64;

    // staging chunk ids: t and t+256; chunk c covers row c/4, 16B part c%4
    const int r0 = t >> 2, p0 = t & 3;
    const int r1 = (t + 256) >> 2, p1 = (t + 256) & 3;

    v_f32x4 acc[4][4] = {};

    for (int k0 = 0; k0 < KDIM; k0 += 32) {
        uint4 a0 = *(const uint4*)(A + (size_t)(m0 + r0) * KDIM + k0 + p0 * 8);
        uint4 a1 = *(const uint4*)(A + (size_t)(m0 + r1) * KDIM + k0 + p1 * 8);
        uint4 b0 = *(const uint4*)(Bt + (size_t)(n0 + r0) * KDIM + k0 + p0 * 8);
        uint4 b1 = *(const uint4*)(Bt + (size_t)(n0 + r1) * KDIM + k0 + p1 * 8);
        __syncthreads();
        *(uint4*)(As + r0 * 32 + p0 * 8) = a0;
        *(uint4*)(As + r1 * 32 + p1 * 8) = a1;
        *(uint4*)(Bs + r0 * 32 + p0 * 8) = b0;
        *(uint4*)(Bs + r1 * 32 + p1 * 8) = b1;
        __syncthreads();

        v_bf16x8 af[4], bfr[4];
        #pragma unroll
        for (int mt = 0; mt < 4; mt++) {
            int r = wRow + mt * 16 + (lane & 15);
            af[mt] = *(const v_bf16x8*)(As + r * 32 + (lane >> 4) * 8);
        }
        #pragma unroll
        for (int nt = 0; nt < 4; nt++) {
            int r = wCol + nt * 16 + (lane & 15);
            bfr[nt] = *(const v_bf16x8*)(Bs + r * 32 + (lane >> 4) * 8);
        }
        #pragma unroll
        for (int mt = 0; mt < 4; mt++)
            #pragma unroll
            for (int nt = 0; nt < 4; nt++)
                acc[mt][nt] = __builtin_amdgcn_mfma_f32_16x16x32_bf16(
                    af[mt], bfr[nt], acc[mt][nt], 0, 0, 0);
    }

    float bv[4];
    #pragma unroll
    for (int nt = 0; nt < 4; nt++) bv[nt] = bias[n0 + wCol + nt * 16 + (lane & 15)];

    #pragma unroll
    for (int mt = 0; mt < 4; mt++) {
        #pragma unroll
        for (int nt = 0; nt < 4; nt++) {
            #pragma unroll
            for (int r = 0; r < 4; r++) {
                int row = m0 + wRow + mt * 16 + (lane >> 4) * 4 + r;
                int col = n0 + wCol + nt * 16 + (lane & 15);
                float v = acc[mt][nt][r] + bv[nt];
                if (MODE == 0) {
                    ((float*)Cv)[(size_t)row * DMODEL + col] = v;
                } else {
                    int b = row >> 11, s = row & (S_LEN - 1);
                    int h = col >> 6, dk = col & (DK - 1);
                    ((bf16*)Cv)[(((size_t)(b * NH + h)) * S_LEN + s) * DK + dk] =
                        __float2bfloat16(v);
                }
            }
        }
    }
}

// ---------------- Flash attention (causal) ----------------
// Q,K,V: [B,H,S,DK] bf16. Output attn_out: [B,S,H,DK] bf16.
// One thread = one query; block = 128 queries of one (b,h). Reversed-y launch
// so the largest-work blocks dispatch first.
#define KT 128
#define QB 128
#define CH 8

__global__ __launch_bounds__(128) void attn_kernel(
    const bf16* __restrict__ Qg, const bf16* __restrict__ Kg,
    const bf16* __restrict__ Vg, bf16* __restrict__ Og)
{
    __shared__ __align__(16) bf16 Ks[KT * DK];
    __shared__ __align__(16) bf16 Vs[KT * DK];

    int bh = blockIdx.x;
    int yy = (gridDim.y - 1) - blockIdx.y;  // big blocks first
    int q0 = yy * QB;
    int t = threadIdx.x;
    int q = q0 + t;
    int b = bh / NH;
    int h = bh % NH;

    float qv[DK];
    {
        const uint4* qp = (const uint4*)(Qg + ((size_t)bh * S_LEN + q) * DK);
        #pragma unroll
        for (int i = 0; i < 8; i++) {
            uint4 u = qp[i];
            const bf162* p2 = (const bf162*)&u;
            #pragma unroll
            for (int j = 0; j < 4; j++) {
                float2 f = __bfloat1622float2(p2[j]);
                qv[i * 8 + j * 2] = f.x;
                qv[i * 8 + j * 2 + 1] = f.y;
            }
        }
    }

    float o[DK] = {};
    float mmax = -1e30f, l = 0.f;
    const size_t baseKV = (size_t)bh * S_LEN * DK;
    int ntiles = yy + 1;  // keys 0 .. q0+127

    for (int tile = 0; tile < ntiles; tile++) {
        int k0 = tile * KT;
        {
            const uint4* kp = (const uint4*)(Kg + baseKV + (size_t)k0 * DK);
            const uint4* vp = (const uint4*)(Vg + baseKV + (size_t)k0 * DK);
            uint4* ks = (uint4*)Ks;
            uint4* vs = (uint4*)Vs;
            #pragma unroll
            for (int i = 0; i < 8; i++) {
                ks[t + 128 * i] = kp[t + 128 * i];
                vs[t + 128 * i] = vp[t + 128 * i];
            }
        }
        __syncthreads();

        int nvalid = q - k0 + 1;
        if (nvalid > KT) nvalid = KT;

        for (int c0 = 0; c0 < KT; c0 += CH) {
            if (c0 >= nvalid) break;
            float sc[CH];
            float cmax = -1e30f;
            #pragma unroll
            for (int j = 0; j < CH; j++) {
                int kk = c0 + j;
                const uint4* kr = (const uint4*)(Ks + (size_t)kk * DK);
                float s = 0.f;
                #pragma unroll
                for (int u = 0; u < 8; u++) {
                    uint4 w = kr[u];
                    const bf162* p2 = (const bf162*)&w;
                    #pragma unroll
                    for (int vv = 0; vv < 4; vv++) {
                        float2 f = __bfloat1622float2(p2[vv]);
                        s = fmaf(qv[u * 8 + vv * 2], f.x, s);
                        s = fmaf(qv[u * 8 + vv * 2 + 1], f.y, s);
                    }
                }
                s *= 0.125f;  // 1/sqrt(64)
                if (kk >= nvalid) s = -1e30f;
                sc[j] = s;
                cmax = fmaxf(cmax, s);
            }
            float mnew = fmaxf(mmax, cmax);
            float alpha = __expf(mmax - mnew);
            #pragma unroll
            for (int d = 0; d < DK; d++) o[d] *= alpha;
            l *= alpha;
            mmax = mnew;
            #pragma unroll
            for (int j = 0; j < CH; j++) {
                float p = __expf(sc[j] - mnew);
                l += p;
                const uint4* vr = (const uint4*)(Vs + (size_t)(c0 + j) * DK);
                #pragma unroll
                for (int u = 0; u < 8; u++) {
                    uint4 w = vr[u];
                    const bf162* p2 = (const bf162*)&w;
                    #pragma unroll
                    for (int vv = 0; vv < 4; vv++) {
                        float2 f = __bfloat1622float2(p2[vv]);
                        o[u * 8 + vv * 2] = fmaf(p, f.x, o[u * 8 + vv * 2]);
                        o[u * 8 + vv * 2 + 1] = fmaf(p, f.y, o[u * 8 + vv * 2 + 1]);
                    }
                }
            }
        }
        __syncthreads();
    }

    float inv = 1.f / l;
    size_t outBase = (((size_t)b * S_LEN + q) * NH + h) * DK;
    bf162* op = (bf162*)(Og + outBase);
    #pragma unroll
    for (int dd = 0; dd < 32; dd++) {
        bf162 r;
        r.x = __float2bfloat16(o[2 * dd] * inv);
        r.y = __float2bfloat16(o[2 * dd + 1] * inv);
        op[dd] = r;
    }
}

extern "C" void kernel_launch(void* const* d_in, const int* in_sizes, int n_in,
                              void* d_out, int out_size, void* d_ws, size_t ws_size,
                              hipStream_t stream) {
    const float* x  = (const float*)d_in[0];
    // d_in[1] = attn_mask (tril) — causality implemented directly
    const float* Wq = (const float*)d_in[2];
    const float* bq = (const float*)d_in[3];
    const float* Wk = (const float*)d_in[4];
    const float* bk = (const float*)d_in[5];
    const float* Wv = (const float*)d_in[6];
    const float* bv = (const float*)d_in[7];
    const float* Wo = (const float*)d_in[8];
    const float* bo = (const float*)d_in[9];
    float* out = (float*)d_out;

    const size_t TEN = (size_t)BATCH * S_LEN * DMODEL * sizeof(bf16);  // 16 MiB
    char* ws = (char*)d_ws;
    bf16* xb = (bf16*)ws;                 // later reused as AO
    bf16* Vt = (bf16*)(ws + TEN);
    bf16* Wt = (bf16*)(ws + 2 * TEN);     // 2 MiB transpose scratch (serialized reuse)
    bf16* Q  = (bf16*)d_out;              // Q,K live in d_out until final GEMM
    bf16* Kt = (bf16*)((char*)d_out + TEN);
    bf16* AO = xb;

    dim3 gT(DMODEL / 32, DMODEL / 32), bT(32, 8);
    dim3 gG(BATCH * S_LEN / 128, DMODEL / 128);  // (64, 8)

    hipLaunchKernelGGL(cvt_f32_bf16, dim3(BATCH * S_LEN * DMODEL / 1024), dim3(256),
                       0, stream, x, xb);

    hipLaunchKernelGGL(transpose_cvt, gT, bT, 0, stream, Wq, Wt);
    hipLaunchKernelGGL((gemm_mfma<1>), gG, dim3(256), 0, stream, xb, Wt, bq, (void*)Q);
    hipLaunchKernelGGL(transpose_cvt, gT, bT, 0, stream, Wk, Wt);
    hipLaunchKernelGGL((gemm_mfma<1>), gG, dim3(256), 0, stream, xb, Wt, bk, (void*)Kt);
    hipLaunchKernelGGL(transpose_cvt, gT, bT, 0, stream, Wv, Wt);
    hipLaunchKernelGGL((gemm_mfma<1>), gG, dim3(256), 0, stream, xb, Wt, bv, (void*)Vt);

    hipLaunchKernelGGL(attn_kernel, dim3(BATCH * NH, S_LEN / QB), dim3(QB),
                       0, stream, Q, Kt, Vt, AO);

    hipLaunchKernelGGL(transpose_cvt, gT, bT, 0, stream, Wo, Wt);
    hipLaunchKernelGGL((gemm_mfma<0>), gG, dim3(256), 0, stream, AO, Wt, bo, (void*)out);
}

// Round 4
// 335.529 us; speedup vs baseline: 9.8543x; 5.3888x over previous
//
#include <hip/hip_runtime.h>
#include <hip/hip_bf16.h>
#include <stdint.h>

#define S_LEN 2048
#define DMODEL 1024
#define NH 16
#define DK 64
#define BATCH 4
#define KDIM 1024

using bf16 = __hip_bfloat16;
using bf162 = __hip_bfloat162;

typedef __bf16 v_bf16x8 __attribute__((ext_vector_type(8)));
typedef float v_f32x4 __attribute__((ext_vector_type(4)));

struct alignas(8) BF16x4 { __bf16 v[4]; };

// ---------- prep: fp32 -> bf16 elementwise (4 elems/thread) ----------
struct alignas(8) BF4 { bf16 a, b, c, d; };

__global__ __launch_bounds__(256) void cvt_f32_bf16(const float* __restrict__ in,
                                                    bf16* __restrict__ out) {
    size_t i = ((size_t)blockIdx.x * 256 + threadIdx.x) * 4;
    float4 v = *(const float4*)(in + i);
    BF4 r;
    r.a = __float2bfloat16(v.x);
    r.b = __float2bfloat16(v.y);
    r.c = __float2bfloat16(v.z);
    r.d = __float2bfloat16(v.w);
    *(BF4*)(out + i) = r;
}

// ---------- prep: W[k][n] fp32 -> Wt[n][k] bf16 (tiled transpose) ----------
__global__ __launch_bounds__(256) void transpose_cvt(const float* __restrict__ W,
                                                     bf16* __restrict__ Wt) {
    __shared__ float tile[32][33];
    int tx = threadIdx.x, ty = threadIdx.y;
    int k0 = blockIdx.x * 32, n0 = blockIdx.y * 32;
    #pragma unroll
    for (int i = 0; i < 4; i++) {
        int k = k0 + ty + 8 * i;
        tile[ty + 8 * i][tx] = W[(size_t)k * DMODEL + n0 + tx];
    }
    __syncthreads();
    #pragma unroll
    for (int i = 0; i < 4; i++) {
        int n = n0 + ty + 8 * i;
        Wt[(size_t)n * DMODEL + k0 + tx] = __float2bfloat16(tile[tx][ty + 8 * i]);
    }
}

// ---------- MFMA GEMM: C = A @ W + bias ----------
// A: [M,1024] bf16 row-major. Bt: [1024,1024] bf16 with Bt[n][k] = W[k][n].
// MODE 0: C fp32 row-major [M,1024].
// MODE 1: C bf16 as [B,H,S,DK]   (row=b*S+s, col=h*DK+dk)
// MODE 2: C bf16 as [B,H,DK,S]   (V transposed for attention B-fragments)
template <int MODE>
__global__ __launch_bounds__(256) void gemm_mfma(
    const bf16* __restrict__ A, const bf16* __restrict__ Bt,
    const float* __restrict__ bias, void* __restrict__ Cv)
{
    __shared__ __align__(16) short As[128 * 32];
    __shared__ __align__(16) short Bs[128 * 32];
    const int t = threadIdx.x;
    const int lane = t & 63;
    const int wave = t >> 6;
    const int m0 = blockIdx.x * 128;
    const int n0 = blockIdx.y * 128;
    const int wRow = (wave >> 1) * 64;
    const int wCol = (wave & 1) * 64;

    const int r0 = t >> 2, p0 = t & 3;
    const int r1 = (t + 256) >> 2, p1 = (t + 256) & 3;

    v_f32x4 acc[4][4] = {};

    for (int k0 = 0; k0 < KDIM; k0 += 32) {
        uint4 a0 = *(const uint4*)(A + (size_t)(m0 + r0) * KDIM + k0 + p0 * 8);
        uint4 a1 = *(const uint4*)(A + (size_t)(m0 + r1) * KDIM + k0 + p1 * 8);
        uint4 b0 = *(const uint4*)(Bt + (size_t)(n0 + r0) * KDIM + k0 + p0 * 8);
        uint4 b1 = *(const uint4*)(Bt + (size_t)(n0 + r1) * KDIM + k0 + p1 * 8);
        __syncthreads();
        *(uint4*)(As + r0 * 32 + p0 * 8) = a0;
        *(uint4*)(As + r1 * 32 + p1 * 8) = a1;
        *(uint4*)(Bs + r0 * 32 + p0 * 8) = b0;
        *(uint4*)(Bs + r1 * 32 + p1 * 8) = b1;
        __syncthreads();

        v_bf16x8 af[4], bfr[4];
        #pragma unroll
        for (int mt = 0; mt < 4; mt++) {
            int r = wRow + mt * 16 + (lane & 15);
            af[mt] = *(const v_bf16x8*)(As + r * 32 + (lane >> 4) * 8);
        }
        #pragma unroll
        for (int nt = 0; nt < 4; nt++) {
            int r = wCol + nt * 16 + (lane & 15);
            bfr[nt] = *(const v_bf16x8*)(Bs + r * 32 + (lane >> 4) * 8);
        }
        #pragma unroll
        for (int mt = 0; mt < 4; mt++)
            #pragma unroll
            for (int nt = 0; nt < 4; nt++)
                acc[mt][nt] = __builtin_amdgcn_mfma_f32_16x16x32_bf16(
                    af[mt], bfr[nt], acc[mt][nt], 0, 0, 0);
    }

    float bv[4];
    #pragma unroll
    for (int nt = 0; nt < 4; nt++) bv[nt] = bias[n0 + wCol + nt * 16 + (lane & 15)];

    #pragma unroll
    for (int mt = 0; mt < 4; mt++) {
        #pragma unroll
        for (int nt = 0; nt < 4; nt++) {
            #pragma unroll
            for (int r = 0; r < 4; r++) {
                int row = m0 + wRow + mt * 16 + (lane >> 4) * 4 + r;
                int col = n0 + wCol + nt * 16 + (lane & 15);
                float v = acc[mt][nt][r] + bv[nt];
                if (MODE == 0) {
                    ((float*)Cv)[(size_t)row * DMODEL + col] = v;
                } else if (MODE == 1) {
                    int b = row >> 11, s = row & (S_LEN - 1);
                    int h = col >> 6, dk = col & (DK - 1);
                    ((bf16*)Cv)[(((size_t)(b * NH + h)) * S_LEN + s) * DK + dk] =
                        __float2bfloat16(v);
                } else {
                    int b = row >> 11, s = row & (S_LEN - 1);
                    int h = col >> 6, dk = col & (DK - 1);
                    ((bf16*)Cv)[(((size_t)(b * NH + h)) * DK + dk) * S_LEN + s] =
                        __float2bfloat16(v);
                }
            }
        }
    }
}

// ---------------- MFMA flash attention (causal) ----------------
// Q,K: [B,H,S,DK] bf16.  Vt: [B,H,DK,S] bf16.  Out: [B,S,H,DK] bf16.
// Block: 256 thr (4 waves), 128 queries of one (b,h); K-tiles of 128 keys.
// S^T = K@Q^T via mfma (C/D: col=query, row=key) -> softmax in-register ->
// P[query][key] through swizzled LDS -> PV via mfma with Vt B-fragments.
__global__ __launch_bounds__(256) void attn_mfma(
    const bf16* __restrict__ Qg, const bf16* __restrict__ Kg,
    const bf16* __restrict__ Vtg, bf16* __restrict__ Og)
{
    __shared__ __align__(16) short Ks[128 * 64];   // [key][dk], 8-chunk XOR swizzle
    __shared__ __align__(16) short Vs[64 * 128];   // [dk][key], 8-chunk XOR swizzle
    __shared__ __align__(16) short Ps[128 * 128];  // [query][key], swizzled

    const int t = threadIdx.x;
    const int lane = t & 63;
    const int wave = t >> 6;
    const int quad = lane >> 4;
    const int l15 = lane & 15;
    const int bh = blockIdx.x;
    const int yy = (gridDim.y - 1) - blockIdx.y;  // biggest blocks first
    const int q0 = yy * 128;

    const size_t baseK = (size_t)bh * S_LEN * DK;
    const size_t baseVt = (size_t)bh * DK * S_LEN;

    // Q fragments (B-operand): qf[qt][kc]; query = q0+wave*32+qt*16+l15
    v_bf16x8 qf[2][2];
    #pragma unroll
    for (int qt = 0; qt < 2; qt++) {
        int q = q0 + wave * 32 + qt * 16 + l15;
        #pragma unroll
        for (int kc = 0; kc < 2; kc++)
            qf[qt][kc] = *(const v_bf16x8*)(Qg + baseK + (size_t)q * DK + kc * 32 + quad * 8);
    }

    v_f32x4 oacc[2][4] = {};          // [qt][dt]  rows=query(quad*4+r), cols=d(l15)
    float mrun[2] = {-1e30f, -1e30f};
    float lrun[2] = {0.f, 0.f};
    const float SC = 0.18033688f;     // (1/8) * log2(e)

    for (int tt = 0; tt <= yy; tt++) {
        int k0 = tt * 128;
        __syncthreads();
        // stage K tile: rows=key(128), 8 chunks of 8 bf16 per row
        #pragma unroll
        for (int i = 0; i < 4; i++) {
            int c = t + 256 * i;
            int r = c >> 3, p = c & 7;
            uint4 val = *(const uint4*)(Kg + baseK + (size_t)(k0 + r) * DK + p * 8);
            *(uint4*)(Ks + r * 64 + (p ^ (r & 7)) * 8) = val;
        }
        // stage Vt tile: rows=d(64), 16 chunks per row
        #pragma unroll
        for (int i = 0; i < 4; i++) {
            int c = t + 256 * i;
            int d = c >> 4, p = c & 15;
            uint4 val = *(const uint4*)(Vtg + baseVt + (size_t)d * S_LEN + k0 + p * 8);
            *(uint4*)(Vs + d * 128 + (p ^ (d & 15)) * 8) = val;
        }
        __syncthreads();

        // ---- S^T = K @ Q^T : s_[kt][qt], rows=key(quad*4+r), cols=query(l15)
        v_f32x4 s_[8][2];
        #pragma unroll
        for (int kt = 0; kt < 8; kt++) {
            int krow = kt * 16 + l15;
            v_bf16x8 kf0 = *(const v_bf16x8*)(Ks + krow * 64 + ((0 * 4 + quad) ^ (krow & 7)) * 8);
            v_bf16x8 kf1 = *(const v_bf16x8*)(Ks + krow * 64 + ((1 * 4 + quad) ^ (krow & 7)) * 8);
            #pragma unroll
            for (int qt = 0; qt < 2; qt++) {
                v_f32x4 a = {};
                a = __builtin_amdgcn_mfma_f32_16x16x32_bf16(kf0, qf[qt][0], a, 0, 0, 0);
                a = __builtin_amdgcn_mfma_f32_16x16x32_bf16(kf1, qf[qt][1], a, 0, 0, 0);
                s_[kt][qt] = a;
            }
        }

        // ---- scale + causal mask + online softmax (log2 domain)
        const bool diag = (tt == yy);
        float tmax[2] = {-1e30f, -1e30f};
        #pragma unroll
        for (int kt = 0; kt < 8; kt++)
            #pragma unroll
            for (int qt = 0; qt < 2; qt++)
                #pragma unroll
                for (int r = 0; r < 4; r++) {
                    float v = s_[kt][qt][r] * SC;
                    if (diag) {
                        int key = kt * 16 + quad * 4 + r;
                        int qq = wave * 32 + qt * 16 + l15;
                        if (key > qq) v = -1e30f;
                    }
                    s_[kt][qt][r] = v;
                    tmax[qt] = fmaxf(tmax[qt], v);
                }
        #pragma unroll
        for (int qt = 0; qt < 2; qt++) {
            tmax[qt] = fmaxf(tmax[qt], __shfl_xor(tmax[qt], 16));
            tmax[qt] = fmaxf(tmax[qt], __shfl_xor(tmax[qt], 32));
        }
        float alpha[2];
        #pragma unroll
        for (int qt = 0; qt < 2; qt++) {
            float mn = fmaxf(mrun[qt], tmax[qt]);
            alpha[qt] = exp2f(mrun[qt] - mn);
            mrun[qt] = mn;
        }
        float lsum[2] = {0.f, 0.f};
        #pragma unroll
        for (int kt = 0; kt < 8; kt++)
            #pragma unroll
            for (int qt = 0; qt < 2; qt++)
                #pragma unroll
                for (int r = 0; r < 4; r++) {
                    float p = exp2f(s_[kt][qt][r] - mrun[qt]);
                    s_[kt][qt][r] = p;
                    lsum[qt] += p;
                }
        #pragma unroll
        for (int qt = 0; qt < 2; qt++) {
            lsum[qt] += __shfl_xor(lsum[qt], 16);
            lsum[qt] += __shfl_xor(lsum[qt], 32);
            lrun[qt] = lrun[qt] * alpha[qt] + lsum[qt];
        }
        // rescale O: rows are queries quad*4+r -> broadcast alpha from col-holders
        #pragma unroll
        for (int qt = 0; qt < 2; qt++) {
            float ar[4];
            #pragma unroll
            for (int r = 0; r < 4; r++) ar[r] = __shfl(alpha[qt], quad * 4 + r);
            #pragma unroll
            for (int dt = 0; dt < 4; dt++)
                #pragma unroll
                for (int r = 0; r < 4; r++) oacc[qt][dt][r] *= ar[r];
        }

        // ---- write P[query][key] to LDS (bf16, swizzled)
        #pragma unroll
        for (int qt = 0; qt < 2; qt++) {
            int rq = wave * 32 + qt * 16 + l15;
            #pragma unroll
            for (int kt = 0; kt < 8; kt++) {
                BF16x4 pk;
                #pragma unroll
                for (int r = 0; r < 4; r++) pk.v[r] = (__bf16)s_[kt][qt][r];
                int ch = kt * 2 + (quad >> 1);
                *(BF16x4*)(Ps + rq * 128 + ((ch ^ (rq & 15)) << 3) + (quad & 1) * 4) = pk;
            }
        }
        __syncthreads();

        // ---- PV: O += P @ V   (A=P rows=query, B=V^T rows=d)
        #pragma unroll
        for (int kc2 = 0; kc2 < 4; kc2++) {
            v_bf16x8 pf[2], vf[4];
            #pragma unroll
            for (int qt = 0; qt < 2; qt++) {
                int rq = wave * 32 + qt * 16 + l15;
                pf[qt] = *(const v_bf16x8*)(Ps + rq * 128 + (((kc2 * 4 + quad) ^ (rq & 15)) << 3));
            }
            #pragma unroll
            for (int dt = 0; dt < 4; dt++) {
                int d = dt * 16 + l15;
                vf[dt] = *(const v_bf16x8*)(Vs + d * 128 + (((kc2 * 4 + quad) ^ (d & 15)) << 3));
            }
            #pragma unroll
            for (int qt = 0; qt < 2; qt++)
                #pragma unroll
                for (int dt = 0; dt < 4; dt++)
                    oacc[qt][dt] = __builtin_amdgcn_mfma_f32_16x16x32_bf16(
                        pf[qt], vf[dt], oacc[qt][dt], 0, 0, 0);
        }
    }

    // ---- normalize and store: out[b][s=q][h][d]
    const int b = bh >> 4, h = bh & 15;
    #pragma unroll
    for (int qt = 0; qt < 2; qt++) {
        float inv = 1.f / lrun[qt];
        float ir[4];
        #pragma unroll
        for (int r = 0; r < 4; r++) ir[r] = __shfl(inv, quad * 4 + r);
        #pragma unroll
        for (int dt = 0; dt < 4; dt++) {
            int d = dt * 16 + l15;
            #pragma unroll
            for (int r = 0; r < 4; r++) {
                int q = q0 + wave * 32 + qt * 16 + quad * 4 + r;
                Og[(((size_t)b * S_LEN + q) * NH + h) * DK + d] =
                    __float2bfloat16(oacc[qt][dt][r] * ir[r]);
            }
        }
    }
}

extern "C" void kernel_launch(void* const* d_in, const int* in_sizes, int n_in,
                              void* d_out, int out_size, void* d_ws, size_t ws_size,
                              hipStream_t stream) {
    const float* x  = (const float*)d_in[0];
    // d_in[1] = attn_mask (tril) — causality implemented directly
    const float* Wq = (const float*)d_in[2];
    const float* bq = (const float*)d_in[3];
    const float* Wk = (const float*)d_in[4];
    const float* bk = (const float*)d_in[5];
    const float* Wv = (const float*)d_in[6];
    const float* bv = (const float*)d_in[7];
    const float* Wo = (const float*)d_in[8];
    const float* bo = (const float*)d_in[9];
    float* out = (float*)d_out;

    const size_t TEN = (size_t)BATCH * S_LEN * DMODEL * sizeof(bf16);  // 16 MiB
    char* ws = (char*)d_ws;
    bf16* xb = (bf16*)ws;                 // later reused as AO
    bf16* Vt = (bf16*)(ws + TEN);         // [B,H,DK,S]
    bf16* Wt = (bf16*)(ws + 2 * TEN);     // 2 MiB transpose scratch
    bf16* Q  = (bf16*)d_out;              // Q,K live in d_out until final GEMM
    bf16* Kt = (bf16*)((char*)d_out + TEN);
    bf16* AO = xb;

    dim3 gT(DMODEL / 32, DMODEL / 32), bT(32, 8);
    dim3 gG(BATCH * S_LEN / 128, DMODEL / 128);  // (64, 8)

    hipLaunchKernelGGL(cvt_f32_bf16, dim3(BATCH * S_LEN * DMODEL / 1024), dim3(256),
                       0, stream, x, xb);

    hipLaunchKernelGGL(transpose_cvt, gT, bT, 0, stream, Wq, Wt);
    hipLaunchKernelGGL((gemm_mfma<1>), gG, dim3(256), 0, stream, xb, Wt, bq, (void*)Q);
    hipLaunchKernelGGL(transpose_cvt, gT, bT, 0, stream, Wk, Wt);
    hipLaunchKernelGGL((gemm_mfma<1>), gG, dim3(256), 0, stream, xb, Wt, bk, (void*)Kt);
    hipLaunchKernelGGL(transpose_cvt, gT, bT, 0, stream, Wv, Wt);
    hipLaunchKernelGGL((gemm_mfma<2>), gG, dim3(256), 0, stream, xb, Wt, bv, (void*)Vt);

    hipLaunchKernelGGL(attn_mfma, dim3(BATCH * NH, S_LEN / 128), dim3(256),
                       0, stream, Q, Kt, Vt, AO);

    hipLaunchKernelGGL(transpose_cvt, gT, bT, 0, stream, Wo, Wt);
    hipLaunchKernelGGL((gemm_mfma<0>), gG, dim3(256), 0, stream, AO, Wt, bo, (void*)out);
}

// Round 5
// 310.326 us; speedup vs baseline: 10.6547x; 1.0812x over previous
//
#include <hip/hip_runtime.h>
#include <hip/hip_bf16.h>
#include <stdint.h>

#define S_LEN 2048
#define DMODEL 1024
#define NH 16
#define DK 64
#define BATCH 4
#define KDIM 1024
#define SCQ 0.18033688f  // (1/8) * log2(e), folded into Wq/bq

using bf16 = __hip_bfloat16;
using bf162 = __hip_bfloat162;

typedef __bf16 v_bf16x8 __attribute__((ext_vector_type(8)));
typedef float v_f32x4 __attribute__((ext_vector_type(4)));

struct alignas(8) BF162x2 { bf162 lo, hi; };

// async global->LDS 16B copy (m97 pattern): LDS dest must be wave-uniform base + lane*16
__device__ __forceinline__ void async_copy16(const void* g, void* l) {
    __builtin_amdgcn_global_load_lds(
        (const __attribute__((address_space(1))) void*)g,
        (__attribute__((address_space(3))) void*)l, 16, 0, 0);
}

// ---------- prep: fp32 -> bf16 elementwise (4 elems/thread) ----------
struct alignas(8) BF4 { bf16 a, b, c, d; };

__global__ __launch_bounds__(256) void cvt_f32_bf16(const float* __restrict__ in,
                                                    bf16* __restrict__ out) {
    size_t i = ((size_t)blockIdx.x * 256 + threadIdx.x) * 4;
    float4 v = *(const float4*)(in + i);
    BF4 r;
    r.a = __float2bfloat16(v.x);
    r.b = __float2bfloat16(v.y);
    r.c = __float2bfloat16(v.z);
    r.d = __float2bfloat16(v.w);
    *(BF4*)(out + i) = r;
}

// ---------- prep: 4x W[k][n] fp32 -> Wt4[z][n][k] bf16; z==0 scaled by SCQ ----------
__global__ __launch_bounds__(256) void transpose_cvt4(
    const float* __restrict__ W0, const float* __restrict__ W1,
    const float* __restrict__ W2, const float* __restrict__ W3,
    bf16* __restrict__ Wt4) {
    __shared__ float tile[32][33];
    const int z = blockIdx.z;
    const float* W = (z == 0) ? W0 : (z == 1) ? W1 : (z == 2) ? W2 : W3;
    bf16* Wt = Wt4 + (size_t)z * DMODEL * DMODEL;
    const float sc = (z == 0) ? SCQ : 1.0f;
    int tx = threadIdx.x, ty = threadIdx.y;
    int k0 = blockIdx.x * 32, n0 = blockIdx.y * 32;
    #pragma unroll
    for (int i = 0; i < 4; i++) {
        int k = k0 + ty + 8 * i;
        tile[ty + 8 * i][tx] = W[(size_t)k * DMODEL + n0 + tx];
    }
    __syncthreads();
    #pragma unroll
    for (int i = 0; i < 4; i++) {
        int n = n0 + ty + 8 * i;
        Wt[(size_t)n * DMODEL + k0 + tx] = __float2bfloat16(tile[tx][ty + 8 * i] * sc);
    }
}

// ---------- fused QKV MFMA GEMM ----------
// A(=xb): [8192,1024] bf16. Wt4: 3 transposed weights bf16 [n][k]. grid.z selects:
//  z=0: Q = (x@Wq + bq)*SCQ  -> [B,H,S,DK] bf16      (scale pre-folded into Wt/bias)
//  z=1: K =  x@Wk + bk       -> [B,H,S,DK] bf16
//  z=2: V^T = (x@Wv + bv)^T  -> [B,H,DK,S] bf16  (operand-swapped: C rows=n, cols=s)
__global__ __launch_bounds__(256) void gemm_qkv(
    const bf16* __restrict__ A, const bf16* __restrict__ Wt4,
    const float* __restrict__ bq, const float* __restrict__ bk,
    const float* __restrict__ bv,
    bf16* __restrict__ Qo, bf16* __restrict__ Ko, bf16* __restrict__ Vto)
{
    __shared__ __align__(16) short As[128 * 32];
    __shared__ __align__(16) short Bs[128 * 32];
    const int z = blockIdx.z;
    const bf16* Bt = Wt4 + (size_t)z * DMODEL * DMODEL;
    const float* bias = (z == 0) ? bq : (z == 1) ? bk : bv;
    const float bsc = (z == 0) ? SCQ : 1.0f;

    const int t = threadIdx.x;
    const int lane = t & 63;
    const int wave = t >> 6;
    const int quad = lane >> 4;
    const int l15 = lane & 15;
    const int m0 = blockIdx.x * 128;
    const int n0 = blockIdx.y * 128;
    const int wRow = (wave >> 1) * 64;
    const int wCol = (wave & 1) * 64;

    const int r0 = t >> 2, p0 = t & 3;
    const int r1 = (t + 256) >> 2, p1 = (t + 256) & 3;

    // operand-swap for z==2: A-frag rows come from Bs (n-dim), B-frag rows from As (s-dim)
    const short* ArowBase = (z == 2) ? Bs : As;
    const short* BrowBase = (z == 2) ? As : Bs;

    v_f32x4 acc[4][4] = {};

    for (int k0 = 0; k0 < KDIM; k0 += 32) {
        async_copy16(A + (size_t)(m0 + r0) * KDIM + k0 + p0 * 8, As + (size_t)t * 8);
        async_copy16(A + (size_t)(m0 + r1) * KDIM + k0 + p1 * 8, As + (size_t)(t + 256) * 8);
        async_copy16(Bt + (size_t)(n0 + r0) * KDIM + k0 + p0 * 8, Bs + (size_t)t * 8);
        async_copy16(Bt + (size_t)(n0 + r1) * KDIM + k0 + p1 * 8, Bs + (size_t)(t + 256) * 8);
        __syncthreads();

        v_bf16x8 af[4], bfr[4];
        #pragma unroll
        for (int mt = 0; mt < 4; mt++) {
            int r = wRow + mt * 16 + l15;
            af[mt] = *(const v_bf16x8*)(ArowBase + r * 32 + quad * 8);
        }
        #pragma unroll
        for (int nt = 0; nt < 4; nt++) {
            int r = wCol + nt * 16 + l15;
            bfr[nt] = *(const v_bf16x8*)(BrowBase + r * 32 + quad * 8);
        }
        #pragma unroll
        for (int mt = 0; mt < 4; mt++)
            #pragma unroll
            for (int nt = 0; nt < 4; nt++)
                acc[mt][nt] = __builtin_amdgcn_mfma_f32_16x16x32_bf16(
                    af[mt], bfr[nt], acc[mt][nt], 0, 0, 0);
        __syncthreads();
    }

    if (z != 2) {
        bf16* C = (z == 0) ? Qo : Ko;
        float bvv[4];
        #pragma unroll
        for (int nt = 0; nt < 4; nt++)
            bvv[nt] = bias[n0 + wCol + nt * 16 + l15] * bsc;
        #pragma unroll
        for (int mt = 0; mt < 4; mt++)
            #pragma unroll
            for (int nt = 0; nt < 4; nt++)
                #pragma unroll
                for (int r = 0; r < 4; r++) {
                    int row = m0 + wRow + mt * 16 + quad * 4 + r;
                    int col = n0 + wCol + nt * 16 + l15;
                    int b = row >> 11, s = row & (S_LEN - 1);
                    int h = col >> 6, dk = col & (DK - 1);
                    C[(((size_t)(b * NH + h)) * S_LEN + s) * DK + dk] =
                        __float2bfloat16(acc[mt][nt][r] + bvv[nt]);
                }
    } else {
        // C rows = n (dk dim), cols = s -> contiguous-s stores into Vt[b,h,dk,s]
        float bvv[4][4];
        #pragma unroll
        for (int mt = 0; mt < 4; mt++)
            #pragma unroll
            for (int r = 0; r < 4; r++)
                bvv[mt][r] = bias[n0 + wRow + mt * 16 + quad * 4 + r];
        #pragma unroll
        for (int mt = 0; mt < 4; mt++)
            #pragma unroll
            for (int nt = 0; nt < 4; nt++)
                #pragma unroll
                for (int r = 0; r < 4; r++) {
                    int ng = n0 + wRow + mt * 16 + quad * 4 + r;
                    int rowg = m0 + wCol + nt * 16 + l15;
                    int b = rowg >> 11, s = rowg & (S_LEN - 1);
                    int h = ng >> 6, dk = ng & (DK - 1);
                    Vto[(((size_t)(b * NH + h)) * DK + dk) * S_LEN + s] =
                        __float2bfloat16(acc[mt][nt][r] + bvv[mt][r]);
                }
    }
}

// ---------- output projection: out = AO @ Wo + bo (fp32 out) ----------
__global__ __launch_bounds__(256) void gemm_o(
    const bf16* __restrict__ A, const bf16* __restrict__ Bt,
    const float* __restrict__ bias, float* __restrict__ C)
{
    __shared__ __align__(16) short As[128 * 32];
    __shared__ __align__(16) short Bs[128 * 32];
    const int t = threadIdx.x;
    const int lane = t & 63;
    const int wave = t >> 6;
    const int quad = lane >> 4;
    const int l15 = lane & 15;
    const int m0 = blockIdx.x * 128;
    const int n0 = blockIdx.y * 128;
    const int wRow = (wave >> 1) * 64;
    const int wCol = (wave & 1) * 64;

    const int r0 = t >> 2, p0 = t & 3;
    const int r1 = (t + 256) >> 2, p1 = (t + 256) & 3;

    v_f32x4 acc[4][4] = {};

    for (int k0 = 0; k0 < KDIM; k0 += 32) {
        async_copy16(A + (size_t)(m0 + r0) * KDIM + k0 + p0 * 8, As + (size_t)t * 8);
        async_copy16(A + (size_t)(m0 + r1) * KDIM + k0 + p1 * 8, As + (size_t)(t + 256) * 8);
        async_copy16(Bt + (size_t)(n0 + r0) * KDIM + k0 + p0 * 8, Bs + (size_t)t * 8);
        async_copy16(Bt + (size_t)(n0 + r1) * KDIM + k0 + p1 * 8, Bs + (size_t)(t + 256) * 8);
        __syncthreads();

        v_bf16x8 af[4], bfr[4];
        #pragma unroll
        for (int mt = 0; mt < 4; mt++) {
            int r = wRow + mt * 16 + l15;
            af[mt] = *(const v_bf16x8*)(As + r * 32 + quad * 8);
        }
        #pragma unroll
        for (int nt = 0; nt < 4; nt++) {
            int r = wCol + nt * 16 + l15;
            bfr[nt] = *(const v_bf16x8*)(Bs + r * 32 + quad * 8);
        }
        #pragma unroll
        for (int mt = 0; mt < 4; mt++)
            #pragma unroll
            for (int nt = 0; nt < 4; nt++)
                acc[mt][nt] = __builtin_amdgcn_mfma_f32_16x16x32_bf16(
                    af[mt], bfr[nt], acc[mt][nt], 0, 0, 0);
        __syncthreads();
    }

    float bvv[4];
    #pragma unroll
    for (int nt = 0; nt < 4; nt++) bvv[nt] = bias[n0 + wCol + nt * 16 + l15];

    #pragma unroll
    for (int mt = 0; mt < 4; mt++)
        #pragma unroll
        for (int nt = 0; nt < 4; nt++)
            #pragma unroll
            for (int r = 0; r < 4; r++) {
                int row = m0 + wRow + mt * 16 + quad * 4 + r;
                int col = n0 + wCol + nt * 16 + l15;
                C[(size_t)row * DMODEL + col] = acc[mt][nt][r] + bvv[nt];
            }
}

// ---------------- MFMA flash attention (causal) ----------------
// Q,K: [B,H,S,DK] bf16 (Q pre-scaled by (1/8)*log2e).  Vt: [B,H,DK,S] bf16.
// Out: [B,S,H,DK] bf16.  Block: 256 thr (4 waves), 128 queries; K-tiles of 128.
__global__ __launch_bounds__(256) void attn_mfma(
    const bf16* __restrict__ Qg, const bf16* __restrict__ Kg,
    const bf16* __restrict__ Vtg, bf16* __restrict__ Og)
{
    __shared__ __align__(16) short Ks[128 * 64];   // [key][dk], XOR swizzle
    __shared__ __align__(16) short Vs[64 * 128];   // [dk][key], XOR swizzle
    __shared__ __align__(16) short Ps[128 * 128];  // [query][key], swizzled

    const int t = threadIdx.x;
    const int lane = t & 63;
    const int wave = t >> 6;
    const int quad = lane >> 4;
    const int l15 = lane & 15;
    const int bh = blockIdx.x;
    const int yy = (gridDim.y - 1) - blockIdx.y;  // biggest blocks first
    const int q0 = yy * 128;

    const size_t baseK = (size_t)bh * S_LEN * DK;
    const size_t baseVt = (size_t)bh * DK * S_LEN;

    v_bf16x8 qf[2][2];
    #pragma unroll
    for (int qt = 0; qt < 2; qt++) {
        int q = q0 + wave * 32 + qt * 16 + l15;
        #pragma unroll
        for (int kc = 0; kc < 2; kc++)
            qf[qt][kc] = *(const v_bf16x8*)(Qg + baseK + (size_t)q * DK + kc * 32 + quad * 8);
    }

    v_f32x4 oacc[2][4] = {};
    float mrun[2] = {-1e30f, -1e30f};
    float lrun[2] = {0.f, 0.f};

    for (int tt = 0; tt <= yy; tt++) {
        int k0 = tt * 128;
        __syncthreads();
        #pragma unroll
        for (int i = 0; i < 4; i++) {
            int c = t + 256 * i;
            int r = c >> 3, p = c & 7;
            uint4 val = *(const uint4*)(Kg + baseK + (size_t)(k0 + r) * DK + p * 8);
            *(uint4*)(Ks + r * 64 + (p ^ (r & 7)) * 8) = val;
        }
        #pragma unroll
        for (int i = 0; i < 4; i++) {
            int c = t + 256 * i;
            int d = c >> 4, p = c & 15;
            uint4 val = *(const uint4*)(Vtg + baseVt + (size_t)d * S_LEN + k0 + p * 8);
            *(uint4*)(Vs + d * 128 + (p ^ (d & 15)) * 8) = val;
        }
        __syncthreads();

        // ---- S^T = K @ Q^T (rows=key, cols=query); Q pre-scaled -> log2-units
        v_f32x4 s_[8][2];
        #pragma unroll
        for (int kt = 0; kt < 8; kt++) {
            int krow = kt * 16 + l15;
            v_bf16x8 kf0 = *(const v_bf16x8*)(Ks + krow * 64 + ((quad) ^ (krow & 7)) * 8);
            v_bf16x8 kf1 = *(const v_bf16x8*)(Ks + krow * 64 + ((4 + quad) ^ (krow & 7)) * 8);
            #pragma unroll
            for (int qt = 0; qt < 2; qt++) {
                v_f32x4 a = {};
                a = __builtin_amdgcn_mfma_f32_16x16x32_bf16(kf0, qf[qt][0], a, 0, 0, 0);
                a = __builtin_amdgcn_mfma_f32_16x16x32_bf16(kf1, qf[qt][1], a, 0, 0, 0);
                s_[kt][qt] = a;
            }
        }

        // ---- causal mask only on the diagonal tile (hoisted out of hot loops)
        if (tt == yy) {
            #pragma unroll
            for (int kt = 0; kt < 8; kt++)
                #pragma unroll
                for (int qt = 0; qt < 2; qt++) {
                    int qq = wave * 32 + qt * 16 + l15;
                    #pragma unroll
                    for (int r = 0; r < 4; r++) {
                        int key = kt * 16 + quad * 4 + r;
                        if (key > qq) s_[kt][qt][r] = -1e30f;
                    }
                }
        }

        float tmax[2] = {-1e30f, -1e30f};
        #pragma unroll
        for (int kt = 0; kt < 8; kt++)
            #pragma unroll
            for (int qt = 0; qt < 2; qt++)
                #pragma unroll
                for (int r = 0; r < 4; r++)
                    tmax[qt] = fmaxf(tmax[qt], s_[kt][qt][r]);
        #pragma unroll
        for (int qt = 0; qt < 2; qt++) {
            tmax[qt] = fmaxf(tmax[qt], __shfl_xor(tmax[qt], 16));
            tmax[qt] = fmaxf(tmax[qt], __shfl_xor(tmax[qt], 32));
        }
        float alpha[2];
        #pragma unroll
        for (int qt = 0; qt < 2; qt++) {
            float mn = fmaxf(mrun[qt], tmax[qt]);
            alpha[qt] = __builtin_amdgcn_exp2f(mrun[qt] - mn);
            mrun[qt] = mn;
        }
        float lsum[2] = {0.f, 0.f};
        #pragma unroll
        for (int kt = 0; kt < 8; kt++)
            #pragma unroll
            for (int qt = 0; qt < 2; qt++)
                #pragma unroll
                for (int r = 0; r < 4; r++) {
                    float p = __builtin_amdgcn_exp2f(s_[kt][qt][r] - mrun[qt]);
                    s_[kt][qt][r] = p;
                    lsum[qt] += p;
                }
        #pragma unroll
        for (int qt = 0; qt < 2; qt++) {
            lsum[qt] += __shfl_xor(lsum[qt], 16);
            lsum[qt] += __shfl_xor(lsum[qt], 32);
            lrun[qt] = lrun[qt] * alpha[qt] + lsum[qt];
        }
        #pragma unroll
        for (int qt = 0; qt < 2; qt++) {
            float ar[4];
            #pragma unroll
            for (int r = 0; r < 4; r++) ar[r] = __shfl(alpha[qt], quad * 4 + r);
            #pragma unroll
            for (int dt = 0; dt < 4; dt++)
                #pragma unroll
                for (int r = 0; r < 4; r++) oacc[qt][dt][r] *= ar[r];
        }

        // ---- pack P[query][key] to LDS via packed cvt
        #pragma unroll
        for (int qt = 0; qt < 2; qt++) {
            int rq = wave * 32 + qt * 16 + l15;
            #pragma unroll
            for (int kt = 0; kt < 8; kt++) {
                BF162x2 pk;
                pk.lo = __float22bfloat162_rn(make_float2(s_[kt][qt][0], s_[kt][qt][1]));
                pk.hi = __float22bfloat162_rn(make_float2(s_[kt][qt][2], s_[kt][qt][3]));
                int ch = kt * 2 + (quad >> 1);
                *(BF162x2*)(Ps + rq * 128 + ((ch ^ (rq & 15)) << 3) + (quad & 1) * 4) = pk;
            }
        }
        __syncthreads();

        // ---- PV: O += P @ V
        #pragma unroll
        for (int kc2 = 0; kc2 < 4; kc2++) {
            v_bf16x8 pf[2], vf[4];
            #pragma unroll
            for (int qt = 0; qt < 2; qt++) {
                int rq = wave * 32 + qt * 16 + l15;
                pf[qt] = *(const v_bf16x8*)(Ps + rq * 128 + (((kc2 * 4 + quad) ^ (rq & 15)) << 3));
            }
            #pragma unroll
            for (int dt = 0; dt < 4; dt++) {
                int d = dt * 16 + l15;
                vf[dt] = *(const v_bf16x8*)(Vs + d * 128 + (((kc2 * 4 + quad) ^ (d & 15)) << 3));
            }
            #pragma unroll
            for (int qt = 0; qt < 2; qt++)
                #pragma unroll
                for (int dt = 0; dt < 4; dt++)
                    oacc[qt][dt] = __builtin_amdgcn_mfma_f32_16x16x32_bf16(
                        pf[qt], vf[dt], oacc[qt][dt], 0, 0, 0);
        }
    }

    const int b = bh >> 4, h = bh & 15;
    #pragma unroll
    for (int qt = 0; qt < 2; qt++) {
        float inv = 1.f / lrun[qt];
        float ir[4];
        #pragma unroll
        for (int r = 0; r < 4; r++) ir[r] = __shfl(inv, quad * 4 + r);
        #pragma unroll
        for (int dt = 0; dt < 4; dt++) {
            int d = dt * 16 + l15;
            #pragma unroll
            for (int r = 0; r < 4; r++) {
                int q = q0 + wave * 32 + qt * 16 + quad * 4 + r;
                Og[(((size_t)b * S_LEN + q) * NH + h) * DK + d] =
                    __float2bfloat16(oacc[qt][dt][r] * ir[r]);
            }
        }
    }
}

extern "C" void kernel_launch(void* const* d_in, const int* in_sizes, int n_in,
                              void* d_out, int out_size, void* d_ws, size_t ws_size,
                              hipStream_t stream) {
    const float* x  = (const float*)d_in[0];
    // d_in[1] = attn_mask (tril) — causality implemented directly
    const float* Wq = (const float*)d_in[2];
    const float* bq = (const float*)d_in[3];
    const float* Wk = (const float*)d_in[4];
    const float* bk = (const float*)d_in[5];
    const float* Wv = (const float*)d_in[6];
    const float* bv = (const float*)d_in[7];
    const float* Wo = (const float*)d_in[8];
    const float* bo = (const float*)d_in[9];
    float* out = (float*)d_out;

    const size_t TEN = (size_t)BATCH * S_LEN * DMODEL * sizeof(bf16);  // 16 MiB
    char* ws = (char*)d_ws;
    bf16* xb  = (bf16*)ws;                 // later reused as AO
    bf16* Vt  = (bf16*)(ws + TEN);         // [B,H,DK,S]
    bf16* Wt4 = (bf16*)(ws + 2 * TEN);     // 4 transposed weights, 8 MiB
    bf16* Q   = (bf16*)d_out;              // Q,K live in d_out until final GEMM
    bf16* Kt  = (bf16*)((char*)d_out + TEN);
    bf16* AO  = xb;

    hipLaunchKernelGGL(cvt_f32_bf16, dim3(BATCH * S_LEN * DMODEL / 1024), dim3(256),
                       0, stream, x, xb);

    hipLaunchKernelGGL(transpose_cvt4, dim3(DMODEL / 32, DMODEL / 32, 4), dim3(32, 8),
                       0, stream, Wq, Wk, Wv, Wo, Wt4);

    hipLaunchKernelGGL(gemm_qkv, dim3(BATCH * S_LEN / 128, DMODEL / 128, 3), dim3(256),
                       0, stream, xb, Wt4, bq, bk, bv, Q, Kt, Vt);

    hipLaunchKernelGGL(attn_mfma, dim3(BATCH * NH, S_LEN / 128), dim3(256),
                       0, stream, Q, Kt, Vt, AO);

    hipLaunchKernelGGL(gemm_o, dim3(BATCH * S_LEN / 128, DMODEL / 128), dim3(256),
                       0, stream, AO, Wt4 + (size_t)3 * DMODEL * DMODEL, bo, out);
}

// Round 6
// 304.439 us; speedup vs baseline: 10.8607x; 1.0193x over previous
//
#include <hip/hip_runtime.h>
#include <hip/hip_bf16.h>
#include <stdint.h>

#define S_LEN 2048
#define DMODEL 1024
#define NH 16
#define DK 64
#define BATCH 4
#define KDIM 1024
#define SCQ 0.18033688f  // (1/8) * log2(e), folded into Wq/bq

using bf16 = __hip_bfloat16;
using bf162 = __hip_bfloat162;

typedef __bf16 v_bf16x8 __attribute__((ext_vector_type(8)));
typedef short v_s16x4 __attribute__((ext_vector_type(4)));
typedef float v_f32x4 __attribute__((ext_vector_type(4)));

union PackB4 { v_s16x4 v; bf162 h[2]; };

// ---------- prep: fp32 -> bf16 elementwise (4 elems/thread) ----------
struct alignas(8) BF4 { bf16 a, b, c, d; };

__global__ __launch_bounds__(256) void cvt_f32_bf16(const float* __restrict__ in,
                                                    bf16* __restrict__ out) {
    size_t i = ((size_t)blockIdx.x * 256 + threadIdx.x) * 4;
    float4 v = *(const float4*)(in + i);
    BF4 r;
    r.a = __float2bfloat16(v.x);
    r.b = __float2bfloat16(v.y);
    r.c = __float2bfloat16(v.z);
    r.d = __float2bfloat16(v.w);
    *(BF4*)(out + i) = r;
}

// ---------- prep: 4x W[k][n] fp32 -> Wt4[z][n][k] bf16; z==0 scaled by SCQ ----------
__global__ __launch_bounds__(256) void transpose_cvt4(
    const float* __restrict__ W0, const float* __restrict__ W1,
    const float* __restrict__ W2, const float* __restrict__ W3,
    bf16* __restrict__ Wt4) {
    __shared__ float tile[32][33];
    const int z = blockIdx.z;
    const float* W = (z == 0) ? W0 : (z == 1) ? W1 : (z == 2) ? W2 : W3;
    bf16* Wt = Wt4 + (size_t)z * DMODEL * DMODEL;
    const float sc = (z == 0) ? SCQ : 1.0f;
    int tx = threadIdx.x, ty = threadIdx.y;
    int k0 = blockIdx.x * 32, n0 = blockIdx.y * 32;
    #pragma unroll
    for (int i = 0; i < 4; i++) {
        int k = k0 + ty + 8 * i;
        tile[ty + 8 * i][tx] = W[(size_t)k * DMODEL + n0 + tx];
    }
    __syncthreads();
    #pragma unroll
    for (int i = 0; i < 4; i++) {
        int n = n0 + ty + 8 * i;
        Wt[(size_t)n * DMODEL + k0 + tx] = __float2bfloat16(tile[tx][ty + 8 * i] * sc);
    }
}

// ---------- fused QKV MFMA GEMM (VGPR-round-trip staging: loads overlap prev MFMA) ----------
//  z=0: Q = (x@Wq + bq)*SCQ  -> [B,H,S,DK] bf16
//  z=1: K =  x@Wk + bk       -> [B,H,S,DK] bf16
//  z=2: V^T = (x@Wv + bv)^T  -> [B,H,DK,S] bf16  (operand-swapped: C rows=dk, cols=s)
__global__ __launch_bounds__(256) void gemm_qkv(
    const bf16* __restrict__ A, const bf16* __restrict__ Wt4,
    const float* __restrict__ bq, const float* __restrict__ bk,
    const float* __restrict__ bv,
    bf16* __restrict__ Qo, bf16* __restrict__ Ko, bf16* __restrict__ Vto)
{
    __shared__ __align__(16) short As[128 * 32];
    __shared__ __align__(16) short Bs[128 * 32];
    const int z = blockIdx.z;
    const bf16* Bt = Wt4 + (size_t)z * DMODEL * DMODEL;
    const float* bias = (z == 0) ? bq : (z == 1) ? bk : bv;
    const float bsc = (z == 0) ? SCQ : 1.0f;

    const int t = threadIdx.x;
    const int lane = t & 63;
    const int wave = t >> 6;
    const int quad = lane >> 4;
    const int l15 = lane & 15;
    const int m0 = blockIdx.x * 128;
    const int n0 = blockIdx.y * 128;
    const int wRow = (wave >> 1) * 64;
    const int wCol = (wave & 1) * 64;

    const int r0 = t >> 2, p0 = t & 3;
    const int r1 = (t + 256) >> 2, p1 = (t + 256) & 3;

    const short* ArowBase = (z == 2) ? Bs : As;
    const short* BrowBase = (z == 2) ? As : Bs;

    v_f32x4 acc[4][4] = {};

    for (int k0 = 0; k0 < KDIM; k0 += 32) {
        uint4 a0 = *(const uint4*)(A + (size_t)(m0 + r0) * KDIM + k0 + p0 * 8);
        uint4 a1 = *(const uint4*)(A + (size_t)(m0 + r1) * KDIM + k0 + p1 * 8);
        uint4 b0 = *(const uint4*)(Bt + (size_t)(n0 + r0) * KDIM + k0 + p0 * 8);
        uint4 b1 = *(const uint4*)(Bt + (size_t)(n0 + r1) * KDIM + k0 + p1 * 8);
        __syncthreads();
        *(uint4*)(As + r0 * 32 + p0 * 8) = a0;
        *(uint4*)(As + r1 * 32 + p1 * 8) = a1;
        *(uint4*)(Bs + r0 * 32 + p0 * 8) = b0;
        *(uint4*)(Bs + r1 * 32 + p1 * 8) = b1;
        __syncthreads();

        v_bf16x8 af[4], bfr[4];
        #pragma unroll
        for (int mt = 0; mt < 4; mt++) {
            int r = wRow + mt * 16 + l15;
            af[mt] = *(const v_bf16x8*)(ArowBase + r * 32 + quad * 8);
        }
        #pragma unroll
        for (int nt = 0; nt < 4; nt++) {
            int r = wCol + nt * 16 + l15;
            bfr[nt] = *(const v_bf16x8*)(BrowBase + r * 32 + quad * 8);
        }
        #pragma unroll
        for (int mt = 0; mt < 4; mt++)
            #pragma unroll
            for (int nt = 0; nt < 4; nt++)
                acc[mt][nt] = __builtin_amdgcn_mfma_f32_16x16x32_bf16(
                    af[mt], bfr[nt], acc[mt][nt], 0, 0, 0);
    }

    if (z != 2) {
        bf16* C = (z == 0) ? Qo : Ko;
        float bvv[4];
        #pragma unroll
        for (int nt = 0; nt < 4; nt++)
            bvv[nt] = bias[n0 + wCol + nt * 16 + l15] * bsc;
        #pragma unroll
        for (int mt = 0; mt < 4; mt++)
            #pragma unroll
            for (int nt = 0; nt < 4; nt++)
                #pragma unroll
                for (int r = 0; r < 4; r++) {
                    int row = m0 + wRow + mt * 16 + quad * 4 + r;
                    int col = n0 + wCol + nt * 16 + l15;
                    int b = row >> 11, s = row & (S_LEN - 1);
                    int h = col >> 6, dk = col & (DK - 1);
                    C[(((size_t)(b * NH + h)) * S_LEN + s) * DK + dk] =
                        __float2bfloat16(acc[mt][nt][r] + bvv[nt]);
                }
    } else {
        float bvv[4][4];
        #pragma unroll
        for (int mt = 0; mt < 4; mt++)
            #pragma unroll
            for (int r = 0; r < 4; r++)
                bvv[mt][r] = bias[n0 + wRow + mt * 16 + quad * 4 + r];
        #pragma unroll
        for (int mt = 0; mt < 4; mt++)
            #pragma unroll
            for (int nt = 0; nt < 4; nt++)
                #pragma unroll
                for (int r = 0; r < 4; r++) {
                    int ng = n0 + wRow + mt * 16 + quad * 4 + r;
                    int rowg = m0 + wCol + nt * 16 + l15;
                    int b = rowg >> 11, s = rowg & (S_LEN - 1);
                    int h = ng >> 6, dk = ng & (DK - 1);
                    Vto[(((size_t)(b * NH + h)) * DK + dk) * S_LEN + s] =
                        __float2bfloat16(acc[mt][nt][r] + bvv[mt][r]);
                }
    }
}

// ---------- output projection: out = AO @ Wo + bo (fp32 out) ----------
__global__ __launch_bounds__(256) void gemm_o(
    const bf16* __restrict__ A, const bf16* __restrict__ Bt,
    const float* __restrict__ bias, float* __restrict__ C)
{
    __shared__ __align__(16) short As[128 * 32];
    __shared__ __align__(16) short Bs[128 * 32];
    const int t = threadIdx.x;
    const int lane = t & 63;
    const int wave = t >> 6;
    const int quad = lane >> 4;
    const int l15 = lane & 15;
    const int m0 = blockIdx.x * 128;
    const int n0 = blockIdx.y * 128;
    const int wRow = (wave >> 1) * 64;
    const int wCol = (wave & 1) * 64;

    const int r0 = t >> 2, p0 = t & 3;
    const int r1 = (t + 256) >> 2, p1 = (t + 256) & 3;

    v_f32x4 acc[4][4] = {};

    for (int k0 = 0; k0 < KDIM; k0 += 32) {
        uint4 a0 = *(const uint4*)(A + (size_t)(m0 + r0) * KDIM + k0 + p0 * 8);
        uint4 a1 = *(const uint4*)(A + (size_t)(m0 + r1) * KDIM + k0 + p1 * 8);
        uint4 b0 = *(const uint4*)(Bt + (size_t)(n0 + r0) * KDIM + k0 + p0 * 8);
        uint4 b1 = *(const uint4*)(Bt + (size_t)(n0 + r1) * KDIM + k0 + p1 * 8);
        __syncthreads();
        *(uint4*)(As + r0 * 32 + p0 * 8) = a0;
        *(uint4*)(As + r1 * 32 + p1 * 8) = a1;
        *(uint4*)(Bs + r0 * 32 + p0 * 8) = b0;
        *(uint4*)(Bs + r1 * 32 + p1 * 8) = b1;
        __syncthreads();

        v_bf16x8 af[4], bfr[4];
        #pragma unroll
        for (int mt = 0; mt < 4; mt++) {
            int r = wRow + mt * 16 + l15;
            af[mt] = *(const v_bf16x8*)(As + r * 32 + quad * 8);
        }
        #pragma unroll
        for (int nt = 0; nt < 4; nt++) {
            int r = wCol + nt * 16 + l15;
            bfr[nt] = *(const v_bf16x8*)(Bs + r * 32 + quad * 8);
        }
        #pragma unroll
        for (int mt = 0; mt < 4; mt++)
            #pragma unroll
            for (int nt = 0; nt < 4; nt++)
                acc[mt][nt] = __builtin_amdgcn_mfma_f32_16x16x32_bf16(
                    af[mt], bfr[nt], acc[mt][nt], 0, 0, 0);
    }

    float bvv[4];
    #pragma unroll
    for (int nt = 0; nt < 4; nt++) bvv[nt] = bias[n0 + wCol + nt * 16 + l15];

    #pragma unroll
    for (int mt = 0; mt < 4; mt++)
        #pragma unroll
        for (int nt = 0; nt < 4; nt++)
            #pragma unroll
            for (int r = 0; r < 4; r++) {
                int row = m0 + wRow + mt * 16 + quad * 4 + r;
                int col = n0 + wCol + nt * 16 + l15;
                C[(size_t)row * DMODEL + col] = acc[mt][nt][r] + bvv[nt];
            }
}

// ---------------- MFMA flash attention (causal), register-P PV ----------------
// Q,K: [B,H,S,DK] bf16 (Q pre-scaled).  Vt: [B,H,DK,S] bf16.  Out: [B,S,H,DK] bf16.
// S^T = K@Q^T (16x16x32; C/D col=query,row=key). The C/D layout IS the B-operand
// layout of mfma_16x16x16bf16_1k, so P^T feeds PV straight from registers:
// O^T = V^T @ P^T. No Ps LDS round-trip, no alpha shuffles.
__global__ __launch_bounds__(256) void attn_mfma(
    const bf16* __restrict__ Qg, const bf16* __restrict__ Kg,
    const bf16* __restrict__ Vtg, bf16* __restrict__ Og)
{
    __shared__ __align__(16) short lds[16896];   // 33 KiB
    short* Ks = lds;          // [128][64] XOR-swizzled (16 KiB)
    short* Vs = lds + 8192;   // [64][136] padded rows (17 KiB)
    // epilogue reuses lds as Ot[128][72]

    const int t = threadIdx.x;
    const int lane = t & 63;
    const int wave = t >> 6;
    const int quad = lane >> 4;
    const int l15 = lane & 15;
    const int bh = blockIdx.x;
    const int yy = (gridDim.y - 1) - blockIdx.y;  // biggest blocks first
    const int q0 = yy * 128;

    const size_t baseK = (size_t)bh * S_LEN * DK;
    const size_t baseVt = (size_t)bh * DK * S_LEN;

    v_bf16x8 qf[2][2];
    #pragma unroll
    for (int qt = 0; qt < 2; qt++) {
        int q = q0 + wave * 32 + qt * 16 + l15;
        #pragma unroll
        for (int kc = 0; kc < 2; kc++)
            qf[qt][kc] = *(const v_bf16x8*)(Qg + baseK + (size_t)q * DK + kc * 32 + quad * 8);
    }

    v_f32x4 oacc[2][4] = {};              // O^T: [qt][dt], rows=d(quad*4+r), cols=q(l15)
    float mrun[2] = {-1e30f, -1e30f};
    float lrun[2] = {0.f, 0.f};

    for (int tt = 0; tt <= yy; tt++) {
        int k0 = tt * 128;
        __syncthreads();
        #pragma unroll
        for (int i = 0; i < 4; i++) {
            int c = t + 256 * i;
            int r = c >> 3, p = c & 7;
            uint4 val = *(const uint4*)(Kg + baseK + (size_t)(k0 + r) * DK + p * 8);
            *(uint4*)(Ks + r * 64 + (p ^ (r & 7)) * 8) = val;
        }
        #pragma unroll
        for (int i = 0; i < 4; i++) {
            int c = t + 256 * i;
            int d = c >> 4, p = c & 15;
            uint4 val = *(const uint4*)(Vtg + baseVt + (size_t)d * S_LEN + k0 + p * 8);
            *(uint4*)(Vs + d * 136 + p * 8) = val;
        }
        __syncthreads();

        // ---- S^T = K @ Q^T (rows=key, cols=query); Q pre-scaled -> log2-units
        v_f32x4 s_[8][2];
        #pragma unroll
        for (int kt = 0; kt < 8; kt++) {
            int krow = kt * 16 + l15;
            v_bf16x8 kf0 = *(const v_bf16x8*)(Ks + krow * 64 + ((quad) ^ (krow & 7)) * 8);
            v_bf16x8 kf1 = *(const v_bf16x8*)(Ks + krow * 64 + ((4 + quad) ^ (krow & 7)) * 8);
            #pragma unroll
            for (int qt = 0; qt < 2; qt++) {
                v_f32x4 a = {};
                a = __builtin_amdgcn_mfma_f32_16x16x32_bf16(kf0, qf[qt][0], a, 0, 0, 0);
                a = __builtin_amdgcn_mfma_f32_16x16x32_bf16(kf1, qf[qt][1], a, 0, 0, 0);
                s_[kt][qt] = a;
            }
        }

        if (tt == yy) {  // causal mask, diagonal tile only
            #pragma unroll
            for (int kt = 0; kt < 8; kt++)
                #pragma unroll
                for (int qt = 0; qt < 2; qt++) {
                    int qq = wave * 32 + qt * 16 + l15;
                    #pragma unroll
                    for (int r = 0; r < 4; r++) {
                        int key = kt * 16 + quad * 4 + r;
                        if (key > qq) s_[kt][qt][r] = -1e30f;
                    }
                }
        }

        float tmax[2] = {-1e30f, -1e30f};
        #pragma unroll
        for (int kt = 0; kt < 8; kt++)
            #pragma unroll
            for (int qt = 0; qt < 2; qt++)
                #pragma unroll
                for (int r = 0; r < 4; r++)
                    tmax[qt] = fmaxf(tmax[qt], s_[kt][qt][r]);
        #pragma unroll
        for (int qt = 0; qt < 2; qt++) {
            tmax[qt] = fmaxf(tmax[qt], __shfl_xor(tmax[qt], 16));
            tmax[qt] = fmaxf(tmax[qt], __shfl_xor(tmax[qt], 32));
        }
        float alpha[2];
        #pragma unroll
        for (int qt = 0; qt < 2; qt++) {
            float mn = fmaxf(mrun[qt], tmax[qt]);
            alpha[qt] = __builtin_amdgcn_exp2f(mrun[qt] - mn);
            mrun[qt] = mn;
        }
        float lsum[2] = {0.f, 0.f};
        #pragma unroll
        for (int kt = 0; kt < 8; kt++)
            #pragma unroll
            for (int qt = 0; qt < 2; qt++)
                #pragma unroll
                for (int r = 0; r < 4; r++) {
                    float p = __builtin_amdgcn_exp2f(s_[kt][qt][r] - mrun[qt]);
                    s_[kt][qt][r] = p;
                    lsum[qt] += p;
                }
        #pragma unroll
        for (int qt = 0; qt < 2; qt++) {
            lsum[qt] += __shfl_xor(lsum[qt], 16);
            lsum[qt] += __shfl_xor(lsum[qt], 32);
            lrun[qt] = lrun[qt] * alpha[qt] + lsum[qt];
        }
        // O^T cols = query = l15 -> alpha applies directly, no shuffles
        #pragma unroll
        for (int qt = 0; qt < 2; qt++)
            #pragma unroll
            for (int dt = 0; dt < 4; dt++)
                #pragma unroll
                for (int r = 0; r < 4; r++)
                    oacc[qt][dt][r] *= alpha[qt];

        // ---- PV: O^T += V^T @ P^T (P from registers, K=16 MFMA)
        #pragma unroll
        for (int kt = 0; kt < 8; kt++) {
            v_s16x4 vf[4];
            #pragma unroll
            for (int dt = 0; dt < 4; dt++)
                vf[dt] = *(const v_s16x4*)(Vs + (dt * 16 + l15) * 136 + kt * 16 + quad * 4);
            #pragma unroll
            for (int qt = 0; qt < 2; qt++) {
                PackB4 pu;
                pu.h[0] = __float22bfloat162_rn(make_float2(s_[kt][qt][0], s_[kt][qt][1]));
                pu.h[1] = __float22bfloat162_rn(make_float2(s_[kt][qt][2], s_[kt][qt][3]));
                #pragma unroll
                for (int dt = 0; dt < 4; dt++)
                    oacc[qt][dt] = __builtin_amdgcn_mfma_f32_16x16x16bf16_1k(
                        vf[dt], pu.v, oacc[qt][dt], 0, 0, 0);
            }
        }
    }

    // ---- epilogue: O^T -> Ot[q][d] in LDS (stride 72), then coalesced store
    __syncthreads();  // Ks/Vs dead for all waves before aliasing as Ot
    #pragma unroll
    for (int qt = 0; qt < 2; qt++) {
        float inv = 1.f / lrun[qt];
        int qloc = wave * 32 + qt * 16 + l15;
        #pragma unroll
        for (int dt = 0; dt < 4; dt++) {
            PackB4 ou;
            ou.h[0] = __float22bfloat162_rn(
                make_float2(oacc[qt][dt][0] * inv, oacc[qt][dt][1] * inv));
            ou.h[1] = __float22bfloat162_rn(
                make_float2(oacc[qt][dt][2] * inv, oacc[qt][dt][3] * inv));
            *(v_s16x4*)(lds + qloc * 72 + dt * 16 + quad * 4) = ou.v;
        }
    }
    __syncthreads();
    {
        const int b = bh >> 4, h = bh & 15;
        int row = t >> 1, half = t & 1;
        size_t gbase = (((size_t)b * S_LEN + q0 + row) * NH + h) * DK + half * 32;
        #pragma unroll
        for (int j = 0; j < 4; j++)
            *(uint4*)(Og + gbase + j * 8) =
                *(const uint4*)(lds + row * 72 + half * 32 + j * 8);
    }
}

extern "C" void kernel_launch(void* const* d_in, const int* in_sizes, int n_in,
                              void* d_out, int out_size, void* d_ws, size_t ws_size,
                              hipStream_t stream) {
    const float* x  = (const float*)d_in[0];
    // d_in[1] = attn_mask (tril) — causality implemented directly
    const float* Wq = (const float*)d_in[2];
    const float* bq = (const float*)d_in[3];
    const float* Wk = (const float*)d_in[4];
    const float* bk = (const float*)d_in[5];
    const float* Wv = (const float*)d_in[6];
    const float* bv = (const float*)d_in[7];
    const float* Wo = (const float*)d_in[8];
    const float* bo = (const float*)d_in[9];
    float* out = (float*)d_out;

    const size_t TEN = (size_t)BATCH * S_LEN * DMODEL * sizeof(bf16);  // 16 MiB
    char* ws = (char*)d_ws;
    bf16* xb  = (bf16*)ws;                 // later reused as AO
    bf16* Vt  = (bf16*)(ws + TEN);         // [B,H,DK,S]
    bf16* Wt4 = (bf16*)(ws + 2 * TEN);     // 4 transposed weights, 8 MiB
    bf16* Q   = (bf16*)d_out;              // Q,K live in d_out until final GEMM
    bf16* Kt  = (bf16*)((char*)d_out + TEN);
    bf16* AO  = xb;

    hipLaunchKernelGGL(cvt_f32_bf16, dim3(BATCH * S_LEN * DMODEL / 1024), dim3(256),
                       0, stream, x, xb);

    hipLaunchKernelGGL(transpose_cvt4, dim3(DMODEL / 32, DMODEL / 32, 4), dim3(32, 8),
                       0, stream, Wq, Wk, Wv, Wo, Wt4);

    hipLaunchKernelGGL(gemm_qkv, dim3(BATCH * S_LEN / 128, DMODEL / 128, 3), dim3(256),
                       0, stream, xb, Wt4, bq, bk, bv, Q, Kt, Vt);

    hipLaunchKernelGGL(attn_mfma, dim3(BATCH * NH, S_LEN / 128), dim3(256),
                       0, stream, Q, Kt, Vt, AO);

    hipLaunchKernelGGL(gemm_o, dim3(BATCH * S_LEN / 128, DMODEL / 128), dim3(256),
                       0, stream, AO, Wt4 + (size_t)3 * DMODEL * DMODEL, bo, out);
}